// Round 4
// baseline (793.045 us; speedup 1.0000x reference)
//
#include <hip/hip_runtime.h>

static constexpr int NN = 100000;   // nodes
static constexpr int NE = 3200000;  // edges
static constexpr float EPS = 1e-5f;
static constexpr int SCAN_B = 256;
static constexpr int NBLK = (NN + SCAN_B - 1) / SCAN_B;   // 391
static constexpr int BSH  = 5;                            // bucket shift
static constexpr int NBUK = NN >> BSH;                    // 3125 (exact)

// ---- histogram of dst ----------------------------------------------------
__global__ void k_hist(const int* __restrict__ dst, int* __restrict__ cnt) {
    int e = blockIdx.x * blockDim.x + threadIdx.x;
    if (e < NE) atomicAdd(&cnt[dst[e]], 1);
}

__global__ void k_dinv(const int* __restrict__ cnt, float* __restrict__ dinv) {
    int i = blockIdx.x * blockDim.x + threadIdx.x;
    if (i < NN) dinv[i] = rsqrtf((float)cnt[i] + 1.0f);
}

// ---- exclusive scan over cnt -> rowp -------------------------------------
__global__ void k_scan1(const int* __restrict__ cnt, int* __restrict__ excl,
                        int* __restrict__ bsum) {
    __shared__ int s[SCAN_B];
    int gid = blockIdx.x * SCAN_B + threadIdx.x;
    int v = (gid < NN) ? cnt[gid] : 0;
    s[threadIdx.x] = v;
    __syncthreads();
    for (int off = 1; off < SCAN_B; off <<= 1) {
        int t = (threadIdx.x >= off) ? s[threadIdx.x - off] : 0;
        __syncthreads();
        s[threadIdx.x] += t;
        __syncthreads();
    }
    if (gid < NN) excl[gid] = s[threadIdx.x] - v;
    if (threadIdx.x == SCAN_B - 1) bsum[blockIdx.x] = s[threadIdx.x];
}

__global__ void k_scan2(int* __restrict__ bsum) {
    __shared__ int s[512];
    int tid = threadIdx.x;
    int v = (tid < NBLK) ? bsum[tid] : 0;
    s[tid] = v;
    __syncthreads();
    for (int off = 1; off < 512; off <<= 1) {
        int t = (tid >= off) ? s[tid - off] : 0;
        __syncthreads();
        s[tid] += t;
        __syncthreads();
    }
    if (tid < NBLK) bsum[tid] = s[tid] - v;
}

__global__ void k_scan3(int* __restrict__ excl, const int* __restrict__ bsum,
                        int* __restrict__ cursor) {
    int i = blockIdx.x * blockDim.x + threadIdx.x;
    if (i < NN) {
        int r = excl[i] + bsum[i / SCAN_B];
        excl[i] = r;
        cursor[i] = r;     // seed fine-fill cursor with row_ptr
    }
}

// ---- seed coarse bucket cursors: bcur[b] = rowp[b<<BSH] ------------------
__global__ void k_bseed(const int* __restrict__ rowp, int* __restrict__ bcur) {
    int b = blockIdx.x * blockDim.x + threadIdx.x;
    if (b < NBUK) bcur[b] = rowp[b << BSH];
}

// ---- pass A: partition edges into coarse buckets (packed payload) --------
__global__ void k_bucket(const int* __restrict__ src, const int* __restrict__ dst,
                         int* __restrict__ bcur, unsigned* __restrict__ ebuf) {
    int e = blockIdx.x * blockDim.x + threadIdx.x;
    if (e >= NE) return;
    int d = dst[e];
    int pos = atomicAdd(&bcur[d >> BSH], 1);
    ebuf[pos] = ((unsigned)(d & ((1 << BSH) - 1)) << 17) | (unsigned)src[e];
}

// ---- pass B: fine fill within bucket (L2-local stripe) -------------------
__global__ void k_fill2(const unsigned* __restrict__ ebuf, const int* __restrict__ rowp,
                        int* __restrict__ cursor, int* __restrict__ csr) {
    int b = blockIdx.x;
    int lo = rowp[b << BSH];
    int hi = (b + 1) << BSH;
    int end = (hi >= NN) ? NE : rowp[hi];
    for (int i = lo + threadIdx.x; i < end; i += blockDim.x) {
        unsigned p = ebuf[i];
        int d = (b << BSH) | (int)(p >> 17);
        int pos = atomicAdd(&cursor[d], 1);
        csr[pos] = (int)(p & 0x1FFFFu);
    }
}

// ---- layer-1 staging: q[i, 0..7] = dinv[i]*x[i, 0..4], pad 0 -------------
__global__ void k_stage1(const float* __restrict__ x, const float* __restrict__ dinv,
                         float* __restrict__ q) {
    int idx = blockIdx.x * blockDim.x + threadIdx.x;
    if (idx >= NN * 8) return;
    int i = idx >> 3, k = idx & 7;
    q[idx] = (k < 5) ? x[i * 5 + k] * dinv[i] : 0.f;
}

// ---- hs = dinv[i] * (in[i,:] @ W), OUTP-padded rows ----------------------
template<int IN, int OUT, int OUTP>
__global__ void k_linear_scale(const float* __restrict__ in, const float* __restrict__ W,
                               const float* __restrict__ dinv, float* __restrict__ hs) {
    int idx = blockIdx.x * blockDim.x + threadIdx.x;
    if (idx >= NN * OUTP) return;
    int i = idx / OUTP, f = idx - i * OUTP;
    float a = 0.f;
    if (f < OUT) {
        #pragma unroll
        for (int k = 0; k < IN; ++k) a += in[i * IN + k] * W[k * OUT + f];
        a *= dinv[i];
    }
    hs[idx] = a;
}

// ---- wave-per-node float4 gather + fused finalize -------------------------
// F = padded feature width (multiple of 4). MODE: 0 scale only (write F),
// 1 bias+relu, 2 bias+bn+relu, 3 bias only + write 3 floats (logits).
template<int F, int MODE>
__global__ void k_gather(const int* __restrict__ row_ptr, const int* __restrict__ cnt,
                         const int* __restrict__ csr, const float* __restrict__ hs,
                         const float* __restrict__ dinv, const float* __restrict__ b,
                         const float* __restrict__ g, const float* __restrict__ be,
                         const float* __restrict__ m, const float* __restrict__ vv,
                         float* __restrict__ out) {
    constexpr int F4  = F / 4;        // lanes per edge
    constexpr int EPI = 64 / F4;      // edges per iteration

    int node = (blockIdx.x * blockDim.x + threadIdx.x) >> 6;
    if (node >= NN) return;
    int lane = threadIdx.x & 63;
    int c = lane & (F4 - 1);          // float4 column within row
    int e = lane / F4;                // edge slot

    int start = row_ptr[node];
    int n     = cnt[node];

    float4 a  = make_float4(0.f, 0.f, 0.f, 0.f);
    float4 a2 = make_float4(0.f, 0.f, 0.f, 0.f);
    for (int j = e; j < n; j += 2 * EPI) {
        int s = csr[start + j];
        float4 v = reinterpret_cast<const float4*>(hs + (size_t)s * F)[c];
        int j2 = j + EPI;
        if (j2 < n) {
            int s2 = csr[start + j2];
            float4 v2 = reinterpret_cast<const float4*>(hs + (size_t)s2 * F)[c];
            a2.x += v2.x; a2.y += v2.y; a2.z += v2.z; a2.w += v2.w;
        }
        a.x += v.x; a.y += v.y; a.z += v.z; a.w += v.w;
    }
    a.x += a2.x; a.y += a2.y; a.z += a2.z; a.w += a2.w;
    #pragma unroll
    for (int mask = F4; mask < 64; mask <<= 1) {
        a.x += __shfl_xor(a.x, mask);
        a.y += __shfl_xor(a.y, mask);
        a.z += __shfl_xor(a.z, mask);
        a.w += __shfl_xor(a.w, mask);
    }

    if (lane < F4) {
        float4 self = reinterpret_cast<const float4*>(hs + (size_t)node * F)[lane];
        float di = dinv[node];
        float4 z;
        z.x = di * (a.x + self.x);
        z.y = di * (a.y + self.y);
        z.z = di * (a.z + self.z);
        z.w = di * (a.w + self.w);
        if constexpr (MODE >= 1) {
            int f0 = lane * 4;
            z.x += b[f0 + 0]; z.y += b[f0 + 1];
            z.z += b[f0 + 2]; z.w += (MODE == 3 ? 0.f : b[f0 + 3]);
            if constexpr (MODE == 2) {
                z.x = (z.x - m[f0+0]) * rsqrtf(vv[f0+0] + EPS) * g[f0+0] + be[f0+0];
                z.y = (z.y - m[f0+1]) * rsqrtf(vv[f0+1] + EPS) * g[f0+1] + be[f0+1];
                z.z = (z.z - m[f0+2]) * rsqrtf(vv[f0+2] + EPS) * g[f0+2] + be[f0+2];
                z.w = (z.w - m[f0+3]) * rsqrtf(vv[f0+3] + EPS) * g[f0+3] + be[f0+3];
            }
            if constexpr (MODE == 1 || MODE == 2) {
                z.x = fmaxf(z.x, 0.f); z.y = fmaxf(z.y, 0.f);
                z.z = fmaxf(z.z, 0.f); z.w = fmaxf(z.w, 0.f);
            }
        }
        if constexpr (MODE == 3) {
            float* o = out + (size_t)node * 3;
            o[0] = z.x; o[1] = z.y; o[2] = z.z;
        } else {
            reinterpret_cast<float4*>(out + (size_t)node * F)[lane] = z;
        }
    }
}

// ---- layer-1 tail: X1 = relu(bn(G[:, :5] @ W1 + b1)) ----------------------
__global__ void k_lin1(const float* __restrict__ G, const float* __restrict__ W1,
                       const float* __restrict__ b1, const float* __restrict__ g1,
                       const float* __restrict__ be1, const float* __restrict__ m1,
                       const float* __restrict__ v1, float* __restrict__ X) {
    int idx = blockIdx.x * blockDim.x + threadIdx.x;
    if (idx >= NN * 64) return;
    int i = idx >> 6, f = idx & 63;
    const float* gr = G + (size_t)i * 8;
    float z = b1[f];
    #pragma unroll
    for (int k = 0; k < 5; ++k) z += gr[k] * W1[k * 64 + f];
    z = (z - m1[f]) * rsqrtf(v1[f] + EPS) * g1[f] + be1[f];
    X[idx] = fmaxf(z, 0.f);
}

extern "C" void kernel_launch(void* const* d_in, const int* in_sizes, int n_in,
                              void* d_out, int out_size, void* d_ws, size_t ws_size,
                              hipStream_t stream) {
    const float* x   = (const float*)d_in[0];
    const int*   src = (const int*)  d_in[1];
    const int*   dst = (const int*)  d_in[2];
    const float* W1  = (const float*)d_in[3];
    const float* b1  = (const float*)d_in[4];
    const float* g1  = (const float*)d_in[5];
    const float* be1 = (const float*)d_in[6];
    const float* m1  = (const float*)d_in[7];
    const float* v1  = (const float*)d_in[8];
    const float* W2  = (const float*)d_in[9];
    const float* b2  = (const float*)d_in[10];
    const float* g2  = (const float*)d_in[11];
    const float* be2 = (const float*)d_in[12];
    const float* m2  = (const float*)d_in[13];
    const float* v2  = (const float*)d_in[14];
    const float* W3  = (const float*)d_in[15];
    const float* b3  = (const float*)d_in[16];
    const float* W4  = (const float*)d_in[17];
    const float* b4  = (const float*)d_in[18];
    float* out = (float*)d_out;

    // workspace layout (4-byte units)
    char* wsb = (char*)d_ws;
    float*    dinv   = (float*)wsb;                    // 100352
    int*      cnt    = (int*)(wsb + 100352ull * 4);
    int*      rowp   = (int*)(wsb + 200704ull * 4);
    int*      bsum   = (int*)(wsb + 301056ull * 4);    // 512
    int*      bcur   = (int*)(wsb + 301568ull * 4);    // 3584 pad
    int*      cursor = (int*)(wsb + 305152ull * 4);
    int*      csr    = (int*)(wsb + 405504ull * 4);    // NE
    float*    HS     = (float*)(wsb + (405504ull + NE) * 4);              // NN*64
    float*    X      = (float*)(wsb + (405504ull + NE + 6400000ull) * 4); // NN*64
    unsigned* ebuf   = (unsigned*)X;  // aliases X: used only before layer 1
    float*    G      = (float*)(wsb + (405504ull + NE + 12800000ull) * 4); // NN*8

    const int BLK = 256;
    const int gE  = (NE + BLK - 1) / BLK;
    const int gN  = (NN + BLK - 1) / BLK;
    const int gW  = (NN * 64 + BLK - 1) / BLK;     // wave-per-node
    auto gNF = [&](int f) { return (NN * f + BLK - 1) / BLK; };

    // ---- CSR build + dinv ----
    hipMemsetAsync(cnt, 0, NN * sizeof(int), stream);
    k_hist <<<gE, BLK, 0, stream>>>(dst, cnt);
    k_dinv <<<gN, BLK, 0, stream>>>(cnt, dinv);
    k_scan1<<<NBLK, SCAN_B, 0, stream>>>(cnt, rowp, bsum);
    k_scan2<<<1, 512, 0, stream>>>(bsum);
    k_scan3<<<gN, BLK, 0, stream>>>(rowp, bsum, cursor);
    k_bseed<<<(NBUK + BLK - 1) / BLK, BLK, 0, stream>>>(rowp, bcur);
    k_bucket<<<gE, BLK, 0, stream>>>(src, dst, bcur, ebuf);
    k_fill2<<<NBUK, BLK, 0, stream>>>(ebuf, rowp, cursor, csr);

    // ---- Layer 1: gather at F_in=5 (pad 8), then 5->64 GEMM + BN + ReLU ----
    k_stage1<<<gNF(8), BLK, 0, stream>>>(x, dinv, HS);
    k_gather<8, 0><<<gW, BLK, 0, stream>>>(rowp, cnt, csr, HS, dinv,
                                           nullptr, nullptr, nullptr, nullptr, nullptr, G);
    k_lin1<<<gNF(64), BLK, 0, stream>>>(G, W1, b1, g1, be1, m1, v1, X);

    // ---- Layer 2: 64 -> 32 GEMM, gather at 32, BN + ReLU ----
    k_linear_scale<64, 32, 32><<<gNF(32), BLK, 0, stream>>>(X, W2, dinv, HS);
    k_gather<32, 2><<<gW, BLK, 0, stream>>>(rowp, cnt, csr, HS, dinv, b2, g2, be2, m2, v2, X);

    // ---- Layer 3: 32 -> 16 GEMM, gather at 16, ReLU ----
    k_linear_scale<32, 16, 16><<<gNF(16), BLK, 0, stream>>>(X, W3, dinv, HS);
    k_gather<16, 1><<<gW, BLK, 0, stream>>>(rowp, cnt, csr, HS, dinv, b3,
                                            nullptr, nullptr, nullptr, nullptr, X);

    // ---- Layer 4: 16 -> 3 GEMM (pad 4), gather at 4, logits ----
    k_linear_scale<16, 3, 4><<<gNF(4), BLK, 0, stream>>>(X, W4, dinv, HS);
    k_gather<4, 3><<<gW, BLK, 0, stream>>>(rowp, cnt, csr, HS, dinv, b4,
                                           nullptr, nullptr, nullptr, nullptr, out);
}